// Round 1
// baseline (978.546 us; speedup 1.0000x reference)
//
#include <hip/hip_runtime.h>

#define DEV __device__ __forceinline__

using short8  = __attribute__((ext_vector_type(8))) short;
using floatx4 = __attribute__((ext_vector_type(4))) float;

DEV unsigned short f2bf(float f) {
  unsigned int u = __float_as_uint(f);
  u += 0x7FFFu + ((u >> 16) & 1u);
  return (unsigned short)(u >> 16);
}
DEV float bf2f(unsigned short u) { return __uint_as_float(((unsigned int)u) << 16); }

DEV void stage16(void* lds, const void* g) {
  __builtin_amdgcn_global_load_lds(
      (__attribute__((address_space(1))) void*)g,
      (__attribute__((address_space(3))) void*)lds, 16, 0, 0);
}

DEV float wave_sum(float x) {
#pragma unroll
  for (int m = 32; m; m >>= 1) x += __shfl_xor(x, m);
  return x;
}
DEV float wave_max(float x) {
#pragma unroll
  for (int m = 32; m; m >>= 1) x = fmaxf(x, __shfl_xor(x, m));
  return x;
}

// ---------------------------------------------------------------------------
// 128x128 tile GEMM core: C = A (MxK, K-major) * Bt^T (Bt NxK, K-major)
// LDS K-chunk XOR swizzle: cell (row, cc) holds global chunk cc^((row>>1)&3)
// -> fragment ds_read_b128 spreads over 8 bank-group starts (2-way, free).
// Outputs optional: Cf (f32 ld N), Cb (bf16 ld N), C2 (f32 ld 2048 + offc2).
// ---------------------------------------------------------------------------
DEV void gemm_core(const short* __restrict__ A, const short* __restrict__ Bt,
                   const float* __restrict__ bias,
                   float* __restrict__ Cf, unsigned short* __restrict__ Cb,
                   float* __restrict__ C2, int offc2,
                   int N, int K, int m0, int n0) {
  __shared__ __align__(16) short As[128 * 32];
  __shared__ __align__(16) short Bs[128 * 32];

  const int t    = threadIdx.x;
  const int lane = t & 63;
  const int w    = t >> 6;
  const int wr   = (w >> 1) * 64;
  const int wc   = (w & 1) * 64;
  const int mr   = lane & 15;
  const int kq   = lane >> 4;
  const int ca   = kq ^ ((mr >> 1) & 3);   // swizzled fragment chunk

  floatx4 acc[4][4];
#pragma unroll
  for (int i = 0; i < 4; ++i)
#pragma unroll
    for (int j = 0; j < 4; ++j)
      acc[i][j] = (floatx4){0.f, 0.f, 0.f, 0.f};

  for (int k0 = 0; k0 < K; k0 += 32) {
#pragma unroll
    for (int i = 0; i < 2; ++i) {
      const int c   = t + i * 256;
      const int row = c >> 2;
      const int cc  = c & 3;
      const int sc  = cc ^ ((row >> 1) & 3);   // swizzled source chunk
      stage16(&As[c * 8], A  + (size_t)(m0 + row) * K + k0 + sc * 8);
      stage16(&Bs[c * 8], Bt + (size_t)(n0 + row) * K + k0 + sc * 8);
    }
    __syncthreads();

    short8 af[4], bf4[4];
#pragma unroll
    for (int i = 0; i < 4; ++i)
      af[i] = *(const short8*)&As[(wr + i * 16 + mr) * 32 + ca * 8];
#pragma unroll
    for (int j = 0; j < 4; ++j)
      bf4[j] = *(const short8*)&Bs[(wc + j * 16 + mr) * 32 + ca * 8];
#pragma unroll
    for (int i = 0; i < 4; ++i)
#pragma unroll
      for (int j = 0; j < 4; ++j)
        acc[i][j] = __builtin_amdgcn_mfma_f32_16x16x32_bf16(af[i], bf4[j], acc[i][j], 0, 0, 0);
    __syncthreads();
  }

  // D layout: col=lane&15, row=(lane>>4)*4+reg  [measured m89/m91]
#pragma unroll
  for (int i = 0; i < 4; ++i) {
#pragma unroll
    for (int r = 0; r < 4; ++r) {
      const int row = m0 + wr + i * 16 + kq * 4 + r;
#pragma unroll
      for (int j = 0; j < 4; ++j) {
        const int col = n0 + wc + j * 16 + mr;
        float vv = acc[i][j][r];
        if (bias) vv += bias[col];
        if (Cf) Cf[(size_t)row * N + col] = vv;
        if (Cb) Cb[(size_t)row * N + col] = f2bf(vv);
        if (C2) C2[(size_t)row * 2048 + offc2 + col] = vv;
      }
    }
  }
}

__global__ __launch_bounds__(256)
void gemm_bt(const short* __restrict__ A, long long sAz,
             const short* __restrict__ Bt, long long sBz,
             const float* __restrict__ bias,
             float* __restrict__ Cf, long long sCfz,
             unsigned short* __restrict__ Cb, long long sCbz,
             float* __restrict__ C2, int offc2,
             int N, int K) {
  const int z = blockIdx.z;
  gemm_core(A + (long long)z * sAz, Bt + (long long)z * sBz, bias,
            Cf ? Cf + (long long)z * sCfz : (float*)0,
            Cb ? Cb + (long long)z * sCbz : (unsigned short*)0,
            C2, offc2, N, K, blockIdx.y * 128, blockIdx.x * 128);
}

// 5 independent projection jobs in one dispatch (M=8192, N=1024, K=1024 each)
struct ProjJob {
  const short* A;
  const short* Bt;
  const float* bias;
  unsigned short* Cb;
  float* C2;
  long long offc2;
};
struct Proj5 { ProjJob j[5]; };

__global__ __launch_bounds__(256)
void gemm_proj5(Proj5 p) {
  ProjJob jb = p.j[0];
#pragma unroll
  for (int i = 1; i < 5; ++i)
    if ((int)blockIdx.z == i) jb = p.j[i];
  gemm_core(jb.A, jb.Bt, jb.bias, (float*)0, jb.Cb, jb.C2, (int)jb.offc2,
            1024, 1024, blockIdx.y * 128, blockIdx.x * 128);
}

// ---------------------------------------------------------------------------
// Multi-job LayerNorm over D=1024, bf16 in (opt. +f32 bias before stats) -> bf16
// ---------------------------------------------------------------------------
struct LnJob {
  const unsigned short* x;  // ld = 1024
  const float* bias;        // optional, added before stats
  const float* g;
  const float* Bb;
  unsigned short* y;        // ld = 1024
  float scale;
};

__global__ __launch_bounds__(256)
void ln_multi(LnJob j0, LnJob j1, LnJob j2, LnJob j3, LnJob j4) {
  LnJob jb = j0;
  if (blockIdx.y == 1) jb = j1;
  else if (blockIdx.y == 2) jb = j2;
  else if (blockIdx.y == 3) jb = j3;
  else if (blockIdx.y == 4) jb = j4;
  const int row = blockIdx.x, t = threadIdx.x;
  const ushort4 xv = ((const ushort4*)(jb.x + (size_t)row * 1024))[t];
  float4 v = {bf2f(xv.x), bf2f(xv.y), bf2f(xv.z), bf2f(xv.w)};
  if (jb.bias) {
    const float4 b4 = ((const float4*)jb.bias)[t];
    v.x += b4.x; v.y += b4.y; v.z += b4.z; v.w += b4.w;
  }
  float s  = v.x + v.y + v.z + v.w;
  float s2 = v.x * v.x + v.y * v.y + v.z * v.z + v.w * v.w;
  s = wave_sum(s);
  s2 = wave_sum(s2);
  __shared__ float r1[4], r2[4];
  const int w = t >> 6, lane = t & 63;
  if (!lane) { r1[w] = s; r2[w] = s2; }
  __syncthreads();
  s  = r1[0] + r1[1] + r1[2] + r1[3];
  s2 = r2[0] + r2[1] + r2[2] + r2[3];
  const float mean = s * (1.f / 1024.f);
  const float var  = s2 * (1.f / 1024.f) - mean * mean;
  const float rstd = 1.f / sqrtf(var + 1e-6f);
  const float4 g4 = ((const float4*)jb.g)[t];
  const float4 b4 = ((const float4*)jb.Bb)[t];
  ushort4 o;
  o.x = f2bf(((v.x - mean) * rstd * g4.x + b4.x) * jb.scale);
  o.y = f2bf(((v.y - mean) * rstd * g4.y + b4.y) * jb.scale);
  o.z = f2bf(((v.z - mean) * rstd * g4.z + b4.z) * jb.scale);
  o.w = f2bf(((v.w - mean) * rstd * g4.w + b4.w) * jb.scale);
  ((ushort4*)(jb.y + (size_t)row * 1024))[t] = o;
}

// ---------------------------------------------------------------------------
// Row softmax over 2048 f32 -> bf16 P (+ optional f32 a2 copy)
// ---------------------------------------------------------------------------
__global__ __launch_bounds__(256)
void softmax_kernel(const float* __restrict__ S, unsigned short* __restrict__ P,
                    float* __restrict__ A2) {
  const int row = blockIdx.x, t = threadIdx.x;
  const float4* sr = (const float4*)(S + (size_t)row * 2048);
  float4 a = sr[t], b = sr[t + 256];
  float m = fmaxf(fmaxf(fmaxf(a.x, a.y), fmaxf(a.z, a.w)),
                  fmaxf(fmaxf(b.x, b.y), fmaxf(b.z, b.w)));
  m = wave_max(m);
  __shared__ float red[4];
  const int w = t >> 6, lane = t & 63;
  if (!lane) red[w] = m;
  __syncthreads();
  m = fmaxf(fmaxf(red[0], red[1]), fmaxf(red[2], red[3]));
  a.x = __expf(a.x - m); a.y = __expf(a.y - m); a.z = __expf(a.z - m); a.w = __expf(a.w - m);
  b.x = __expf(b.x - m); b.y = __expf(b.y - m); b.z = __expf(b.z - m); b.w = __expf(b.w - m);
  float s = a.x + a.y + a.z + a.w + b.x + b.y + b.z + b.w;
  s = wave_sum(s);
  __syncthreads();
  if (!lane) red[w] = s;
  __syncthreads();
  s = red[0] + red[1] + red[2] + red[3];
  const float inv = 1.f / s;
  a.x *= inv; a.y *= inv; a.z *= inv; a.w *= inv;
  b.x *= inv; b.y *= inv; b.z *= inv; b.w *= inv;
  ushort4 o0, o1;
  o0.x = f2bf(a.x); o0.y = f2bf(a.y); o0.z = f2bf(a.z); o0.w = f2bf(a.w);
  o1.x = f2bf(b.x); o1.y = f2bf(b.y); o1.z = f2bf(b.z); o1.w = f2bf(b.w);
  ((ushort4*)(P + (size_t)row * 2048))[t] = o0;
  ((ushort4*)(P + (size_t)row * 2048))[t + 256] = o1;
  if (A2) {
    float4* ar = (float4*)(A2 + (size_t)row * 2048);
    ar[t] = a;
    ar[t + 256] = b;
  }
}

// ---------------------------------------------------------------------------
__global__ __launch_bounds__(256)
void cast3_kernel(const float* __restrict__ x0, const float* __restrict__ x1,
                  const float* __restrict__ x2, unsigned short* __restrict__ y0,
                  unsigned short* __restrict__ y1, unsigned short* __restrict__ y2) {
  const float* x = blockIdx.y == 0 ? x0 : (blockIdx.y == 1 ? x1 : x2);
  unsigned short* y = blockIdx.y == 0 ? y0 : (blockIdx.y == 1 ? y1 : y2);
  const int i = blockIdx.x * 256 + threadIdx.x;
  const float4 v = ((const float4*)x)[i];
  ushort4 o;
  o.x = f2bf(v.x); o.y = f2bf(v.y); o.z = f2bf(v.z); o.w = f2bf(v.w);
  ((ushort4*)y)[i] = o;
}

struct W8 {
  const float* src[8];
  unsigned short* dst[8];
};

__global__ __launch_bounds__(256)
void transpose_w8_kernel(W8 p) {
  __shared__ unsigned short tile[64][65];
  const float* in = p.src[blockIdx.z];
  unsigned short* out = p.dst[blockIdx.z];
  const int tr0 = blockIdx.y * 64, tc0 = blockIdx.x * 64;
  const int x = threadIdx.x & 63, y = threadIdx.x >> 6;
#pragma unroll
  for (int i = 0; i < 16; ++i) {
    const int r = i * 4 + y;
    tile[r][x] = f2bf(in[(size_t)(tr0 + r) * 1024 + tc0 + x]);
  }
  __syncthreads();
#pragma unroll
  for (int i = 0; i < 16; ++i) {
    const int r = i * 4 + y;
    out[(size_t)(tc0 + r) * 1024 + tr0 + x] = tile[x][r];
  }
}

__global__ __launch_bounds__(256)
void transpose_v8_kernel(const unsigned short* __restrict__ in0,
                         const unsigned short* __restrict__ in1,
                         unsigned short* __restrict__ out0,
                         unsigned short* __restrict__ out1) {
  __shared__ unsigned short tile[64][65];
  const int zz = blockIdx.z & 3;
  const unsigned short* in = (blockIdx.z < 4 ? in0 : in1) + (size_t)zz * 2048 * 1024;
  unsigned short* out = (blockIdx.z < 4 ? out0 : out1) + (size_t)zz * 1024 * 2048;
  const int tr0 = blockIdx.y * 64, tc0 = blockIdx.x * 64;
  const int x = threadIdx.x & 63, y = threadIdx.x >> 6;
#pragma unroll
  for (int i = 0; i < 16; ++i) {
    const int r = i * 4 + y;
    tile[r][x] = in[(size_t)(tr0 + r) * 1024 + tc0 + x];
  }
  __syncthreads();
#pragma unroll
  for (int i = 0; i < 16; ++i) {
    const int r = i * 4 + y;
    out[(size_t)(tc0 + r) * 2048 + tr0 + x] = tile[x][r];
  }
}

// ---------------------------------------------------------------------------
extern "C" void kernel_launch(void* const* d_in, const int* in_sizes, int n_in,
                              void* d_out, int out_size, void* d_ws, size_t ws_size,
                              hipStream_t stream) {
  const float* q = (const float*)d_in[0];
  const float* k = (const float*)d_in[1];
  const float* v = (const float*)d_in[2];
  const float* W[8];
  const float* bW[8];
  for (int i = 0; i < 8; ++i) {
    W[i]  = (const float*)d_in[3 + 2 * i];
    bW[i] = (const float*)d_in[4 + 2 * i];
  }
  const float* g_[6];
  const float* B_[6];
  for (int i = 0; i < 6; ++i) {
    g_[i] = (const float*)d_in[19 + 2 * i];
    B_[i] = (const float*)d_in[20 + 2 * i];
  }

  float* out_p = (float*)d_out;          // (4,2048,1024)
  float* res_p = out_p + 8388608;        // (8192,2048)
  float* a2_p  = res_p + 16777216;       // (4,2048,2048)

  // workspace layout (~338 MB)
  char* ws = (char*)d_ws;
  const size_t MBy = 1u << 20;
  unsigned short* WT   = (unsigned short*)ws;                 // 8 x 2MB
  unsigned short* qb   = (unsigned short*)(ws + 16 * MBy);
  unsigned short* kb   = (unsigned short*)(ws + 32 * MBy);
  unsigned short* vb   = (unsigned short*)(ws + 48 * MBy);
  unsigned short* pb   = (unsigned short*)(ws + 64 * MBy);    // 5 x 16MB proj slices
  float* Sbuf          = (float*)(ws + 64 * MBy);             // 67MB, aliases pb (dead after LN)
  unsigned short* lnq  = (unsigned short*)(ws + 144 * MBy);
  unsigned short* lnk1 = (unsigned short*)(ws + 160 * MBy);
  unsigned short* lnk2 = (unsigned short*)(ws + 176 * MBy);
  unsigned short* lnv1 = (unsigned short*)(ws + 192 * MBy);
  unsigned short* lnv2 = (unsigned short*)(ws + 208 * MBy);
  unsigned short* lnvT1= (unsigned short*)(ws + 224 * MBy);
  unsigned short* lnvT2= (unsigned short*)(ws + 240 * MBy);
  unsigned short* P    = (unsigned short*)(ws + 256 * MBy);   // 33MB
  unsigned short* ofb  = (unsigned short*)(ws + 290 * MBy);
  unsigned short* ob   = (unsigned short*)(ws + 306 * MBy);
  unsigned short* qf2b = (unsigned short*)(ws + 322 * MBy);

  const size_t SL = 8192ull * 1024;  // proj slice elements

  auto gemm = [&](const unsigned short* A, long long sAz,
                  const unsigned short* Bt, long long sBz, const float* bias,
                  float* Cf, long long sCfz, unsigned short* Cb, long long sCbz,
                  float* C2, int offc2, int M, int N, int K, int Z) {
    dim3 grid(N / 128, M / 128, Z);
    gemm_bt<<<grid, 256, 0, stream>>>((const short*)A, sAz, (const short*)Bt, sBz,
                                      bias, Cf, sCfz, Cb, sCbz, C2, offc2, N, K);
  };
  LnJob nil{};

  // ---- prep ----
  cast3_kernel<<<dim3(8192, 3), 256, 0, stream>>>(q, k, v, qb, kb, vb);
  W8 w8;
  for (int i = 0; i < 8; ++i) { w8.src[i] = W[i]; w8.dst[i] = WT + (size_t)i * 1048576; }
  transpose_w8_kernel<<<dim3(16, 16, 8), 256, 0, stream>>>(w8);

  // ---- all 5 projections in one dispatch (k1,k2,v1,v2,q1) ----
  {
    Proj5 p;
    p.j[0] = {(const short*)kb, (const short*)(WT + 1u * 1048576), 0, pb + 0 * SL, 0, 0};
    p.j[1] = {(const short*)kb, (const short*)(WT + 5u * 1048576), 0, pb + 1 * SL, 0, 0};
    p.j[2] = {(const short*)vb, (const short*)(WT + 2u * 1048576), 0, pb + 2 * SL, 0, 0};
    p.j[3] = {(const short*)vb, (const short*)(WT + 6u * 1048576), 0, pb + 3 * SL, 0, 0};
    p.j[4] = {(const short*)qb, (const short*)(WT + 0u * 1048576), bW[0], pb + 4 * SL, res_p, 0};
    gemm_proj5<<<dim3(8, 64, 5), 256, 0, stream>>>(p);
  }

  // ---- all 5 first-phase LayerNorms in one dispatch ----
  {
    LnJob jk1{pb + 0 * SL, bW[1], g_[1], B_[1], lnk1, 1.f};
    LnJob jk2{pb + 1 * SL, bW[5], g_[4], B_[4], lnk2, 1.f};
    LnJob jv1{pb + 2 * SL, bW[2], g_[2], B_[2], lnv1, 1.f};
    LnJob jv2{pb + 3 * SL, bW[6], g_[5], B_[5], lnv2, 1.f};
    LnJob jq1{pb + 4 * SL, 0,     g_[0], B_[0], lnq,  1.f / 32.f};
    ln_multi<<<dim3(8192, 5), 256, 0, stream>>>(jk1, jk2, jv1, jv2, jq1);
  }
  transpose_v8_kernel<<<dim3(16, 32, 8), 256, 0, stream>>>(lnv1, lnv2, lnvT1, lnvT2);

  // ---- layer 1 attention ----
  gemm(lnq, 2048ll * 1024, lnk1, 2048ll * 1024, 0, Sbuf, 2048ll * 2048, 0, 0, 0, 0,
       2048, 2048, 1024, 4);
  softmax_kernel<<<8192, 256, 0, stream>>>(Sbuf, P, (float*)0);
  gemm(P, 2048ll * 2048, lnvT1, 1024ll * 2048, 0, 0, 0, ob, 2048ll * 1024, 0, 0,
       2048, 1024, 2048, 4);
  gemm(ob, 0, WT + 3u * 1048576, 0, bW[3], 0, 0, ofb, 0, 0, 0, 8192, 1024, 1024, 1);

  // ---- layer 2 ----
  gemm(ofb, 0, WT + 4u * 1048576, 0, bW[4], 0, 0, qf2b, 0, res_p, 1024, 8192, 1024, 1024, 1);
  {
    LnJob jq2{qf2b, 0, g_[3], B_[3], lnq, 1.f / 32.f};
    ln_multi<<<dim3(8192, 1), 256, 0, stream>>>(jq2, nil, nil, nil, nil);
  }
  gemm(lnq, 2048ll * 1024, lnk2, 2048ll * 1024, 0, Sbuf, 2048ll * 2048, 0, 0, 0, 0,
       2048, 2048, 1024, 4);
  softmax_kernel<<<8192, 256, 0, stream>>>(Sbuf, P, a2_p);
  gemm(P, 2048ll * 2048, lnvT2, 1024ll * 2048, 0, 0, 0, ob, 2048ll * 1024, 0, 0,
       2048, 1024, 2048, 4);
  gemm(ob, 0, WT + 7u * 1048576, 0, bW[7], out_p, 0, 0, 0, 0, 0, 8192, 1024, 1024, 1);
}

// Round 2
// 862.850 us; speedup vs baseline: 1.1341x; 1.1341x over previous
//
#include <hip/hip_runtime.h>

#define DEV __device__ __forceinline__

using short8  = __attribute__((ext_vector_type(8))) short;
using floatx4 = __attribute__((ext_vector_type(4))) float;

DEV unsigned short f2bf(float f) {
  unsigned int u = __float_as_uint(f);
  u += 0x7FFFu + ((u >> 16) & 1u);
  return (unsigned short)(u >> 16);
}
DEV float bf2f(unsigned short u) { return __uint_as_float(((unsigned int)u) << 16); }

DEV void stage16(void* lds, const void* g) {
  __builtin_amdgcn_global_load_lds(
      (__attribute__((address_space(1))) void*)g,
      (__attribute__((address_space(3))) void*)lds, 16, 0, 0);
}

DEV float wave_sum(float x) {
#pragma unroll
  for (int m = 32; m; m >>= 1) x += __shfl_xor(x, m);
  return x;
}
DEV float wave_max(float x) {
#pragma unroll
  for (int m = 32; m; m >>= 1) x = fmaxf(x, __shfl_xor(x, m));
  return x;
}

// ---------------------------------------------------------------------------
// Deep-pipelined 128x128 GEMM core: C = A (MxK, K-major) * Bt^T (Bt NxK).
// BK=32, 4 waves (2x4... 2x2 of 64x64 per-wave tiles), 4 LDS buffers =
// 3-tile-deep global_load_lds prefetch with counted vmcnt (never 0 in
// steady state), one s_barrier per K-tile. LDS layout: 16x32 bf16 subtiles
// (1 KB), col ^= 16 when (row&8) -> bank-balanced ds_read_b128 (8/bank,
// the wave64 minimum) AND contiguous-per-lane DMA writes.
// Race-freedom: lgkmcnt(0) before each barrier => every wave's reads of
// buffer (t-1)&3 are complete in registers before any wave can issue the
// stage of tile t+3 into that same buffer (issue is after the barrier).
// vmcnt(8)=2 tiles * 4 loads outstanding allowed => tile t's 4 loads (and
// all older) have landed before any wave passes the barrier and reads it.
// ---------------------------------------------------------------------------
DEV void g128_core(const short* __restrict__ A, const short* __restrict__ Bt,
                   const float* __restrict__ bias,
                   float* __restrict__ Cf, unsigned short* __restrict__ Cb,
                   float* __restrict__ C2, int offc2,
                   int N, int K, int m0, int n0) {
  __shared__ __align__(16) short lds[4][8192];  // per buf: A[0..4095], B[4096..8191]

  const int t    = threadIdx.x;
  const int lane = t & 63;
  const int w    = t >> 6;        // 0..3
  const int wm   = w >> 1;        // 0..1 : owns rows wm*64..+63
  const int wn   = w & 1;         // 0..1 : owns cols wn*64..+63
  const int NT   = K >> 5;        // K-tiles of 32

  // staging geometry: waves 0,1 stage A (8 subtiles), waves 2,3 stage B.
  // wave stages 4 subtiles; lane l writes subtile bytes l*16..+15:
  //   r = l>>2, slot-col = (l&3)*8, holding global col ((l&3)*8)^((l>>5)<<4).
  const int isB  = w >> 1;
  const int row0 = (isB ? n0 : m0) + (w & 1) * 64 + (lane >> 2);
  const int csw  = ((lane & 3) * 8) ^ ((lane >> 5) << 4);
  const short* gbase = isB ? Bt : A;
  const short* gp[4];
#pragma unroll
  for (int i = 0; i < 4; ++i)
    gp[i] = gbase + (size_t)(row0 + i * 16) * K + csw;
  const int ldst = isB * 4096 + (w & 1) * 2048 + lane * 8;

  auto stage = [&](int tt) {
    short* dst = &lds[tt & 3][ldst];
    const int go = tt * 32;
#pragma unroll
    for (int i = 0; i < 4; ++i)
      stage16(dst + i * 512, gp[i] + go);
  };

  floatx4 acc[4][4];
#pragma unroll
  for (int i = 0; i < 4; ++i)
#pragma unroll
    for (int j = 0; j < 4; ++j)
      acc[i][j] = (floatx4){0.f, 0.f, 0.f, 0.f};

  stage(0); stage(1); stage(2);

  // fragment read offset within a subtile-row block:
  //   row = base + mr, k-col = q*8 (swizzled)
  const int mr = lane & 15, q = lane >> 4;
  const int fo = mr * 32 + ((q * 8) ^ ((mr & 8) << 1));

  for (int kt = 0; kt < NT; ++kt) {
    asm volatile("s_waitcnt lgkmcnt(0)" ::: "memory");
    const int rem = NT - 1 - kt;
    if (rem >= 2)      asm volatile("s_waitcnt vmcnt(8)" ::: "memory");
    else if (rem == 1) asm volatile("s_waitcnt vmcnt(4)" ::: "memory");
    else               asm volatile("s_waitcnt vmcnt(0)" ::: "memory");
    __builtin_amdgcn_s_barrier();
    __builtin_amdgcn_sched_barrier(0);

    if (kt + 3 < NT) stage(kt + 3);

    const short* bufA = &lds[kt & 3][wm * 2048];
    const short* bufB = &lds[kt & 3][4096 + wn * 2048];
    short8 a[4], b[4];
#pragma unroll
    for (int m = 0; m < 4; ++m) a[m] = *(const short8*)&bufA[m * 512 + fo];
#pragma unroll
    for (int n = 0; n < 4; ++n) b[n] = *(const short8*)&bufB[n * 512 + fo];

    __builtin_amdgcn_s_setprio(1);
#pragma unroll
    for (int m = 0; m < 4; ++m)
#pragma unroll
      for (int n = 0; n < 4; ++n)
        acc[m][n] = __builtin_amdgcn_mfma_f32_16x16x32_bf16(a[m], b[n], acc[m][n], 0, 0, 0);
    __builtin_amdgcn_s_setprio(0);
  }

  // D layout: col=lane&15, row=(lane>>4)*4+reg  [measured m89/m91]
#pragma unroll
  for (int m = 0; m < 4; ++m) {
#pragma unroll
    for (int r = 0; r < 4; ++r) {
      const int row = m0 + wm * 64 + m * 16 + q * 4 + r;
#pragma unroll
      for (int n = 0; n < 4; ++n) {
        const int col = n0 + wn * 64 + n * 16 + mr;
        float vv = acc[m][n][r];
        if (bias) vv += bias[col];
        if (Cf) Cf[(size_t)row * N + col] = vv;
        if (Cb) Cb[(size_t)row * N + col] = f2bf(vv);
        if (C2) C2[(size_t)row * 2048 + offc2 + col] = vv;
      }
    }
  }
}

// bijective XCD-aware swizzle of the flattened block id (m204 form)
DEV void xcd_decode(int gx, int gy, int& bx, int& by, int& bz) {
  const int nwg = gx * gy * gridDim.z;
  int bid = ((int)blockIdx.z * gy + (int)blockIdx.y) * gx + (int)blockIdx.x;
  const int qq = nwg >> 3, rr = nwg & 7;
  const int xcd = bid & 7, jj = bid >> 3;
  bid = (xcd < rr ? xcd * (qq + 1) : rr * (qq + 1) + (xcd - rr) * qq) + jj;
  bx = bid % gx;
  const int tmp = bid / gx;
  by = tmp % gy;
  bz = tmp / gy;
}

__global__ __launch_bounds__(256)
void g128_bt(const short* __restrict__ A, long long sAz,
             const short* __restrict__ Bt, long long sBz,
             const float* __restrict__ bias,
             float* __restrict__ Cf, long long sCfz,
             unsigned short* __restrict__ Cb, long long sCbz,
             float* __restrict__ C2, int offc2,
             int N, int K) {
  int bx, by, bz;
  xcd_decode(gridDim.x, gridDim.y, bx, by, bz);
  g128_core(A + (long long)bz * sAz, Bt + (long long)bz * sBz, bias,
            Cf ? Cf + (long long)bz * sCfz : (float*)0,
            Cb ? Cb + (long long)bz * sCbz : (unsigned short*)0,
            C2, offc2, N, K, by * 128, bx * 128);
}

// 5 independent projection jobs in one dispatch (M=8192, N=1024, K=1024 each)
struct ProjJob {
  const short* A;
  const short* Bt;
  const float* bias;
  unsigned short* Cb;
  float* C2;
  long long offc2;
};
struct Proj5 { ProjJob j[5]; };

__global__ __launch_bounds__(256)
void g128_proj5(Proj5 p) {
  int bx, by, bz;
  xcd_decode(gridDim.x, gridDim.y, bx, by, bz);
  ProjJob jb = p.j[0];
#pragma unroll
  for (int i = 1; i < 5; ++i)
    if (bz == i) jb = p.j[i];
  g128_core(jb.A, jb.Bt, jb.bias, (float*)0, jb.Cb, jb.C2, (int)jb.offc2,
            1024, 1024, by * 128, bx * 128);
}

// ---------------------------------------------------------------------------
// Multi-job LayerNorm over D=1024, bf16 in (opt. +f32 bias before stats) -> bf16
// ---------------------------------------------------------------------------
struct LnJob {
  const unsigned short* x;  // ld = 1024
  const float* bias;        // optional, added before stats
  const float* g;
  const float* Bb;
  unsigned short* y;        // ld = 1024
  float scale;
};

__global__ __launch_bounds__(256)
void ln_multi(LnJob j0, LnJob j1, LnJob j2, LnJob j3, LnJob j4) {
  LnJob jb = j0;
  if (blockIdx.y == 1) jb = j1;
  else if (blockIdx.y == 2) jb = j2;
  else if (blockIdx.y == 3) jb = j3;
  else if (blockIdx.y == 4) jb = j4;
  const int row = blockIdx.x, t = threadIdx.x;
  const ushort4 xv = ((const ushort4*)(jb.x + (size_t)row * 1024))[t];
  float4 v = {bf2f(xv.x), bf2f(xv.y), bf2f(xv.z), bf2f(xv.w)};
  if (jb.bias) {
    const float4 b4 = ((const float4*)jb.bias)[t];
    v.x += b4.x; v.y += b4.y; v.z += b4.z; v.w += b4.w;
  }
  float s  = v.x + v.y + v.z + v.w;
  float s2 = v.x * v.x + v.y * v.y + v.z * v.z + v.w * v.w;
  s = wave_sum(s);
  s2 = wave_sum(s2);
  __shared__ float r1[4], r2[4];
  const int w = t >> 6, lane = t & 63;
  if (!lane) { r1[w] = s; r2[w] = s2; }
  __syncthreads();
  s  = r1[0] + r1[1] + r1[2] + r1[3];
  s2 = r2[0] + r2[1] + r2[2] + r2[3];
  const float mean = s * (1.f / 1024.f);
  const float var  = s2 * (1.f / 1024.f) - mean * mean;
  const float rstd = 1.f / sqrtf(var + 1e-6f);
  const float4 g4 = ((const float4*)jb.g)[t];
  const float4 b4 = ((const float4*)jb.Bb)[t];
  ushort4 o;
  o.x = f2bf(((v.x - mean) * rstd * g4.x + b4.x) * jb.scale);
  o.y = f2bf(((v.y - mean) * rstd * g4.y + b4.y) * jb.scale);
  o.z = f2bf(((v.z - mean) * rstd * g4.z + b4.z) * jb.scale);
  o.w = f2bf(((v.w - mean) * rstd * g4.w + b4.w) * jb.scale);
  ((ushort4*)(jb.y + (size_t)row * 1024))[t] = o;
}

// ---------------------------------------------------------------------------
// Row softmax over 2048 f32 -> bf16 P (+ optional f32 a2 copy)
// ---------------------------------------------------------------------------
__global__ __launch_bounds__(256)
void softmax_kernel(const float* __restrict__ S, unsigned short* __restrict__ P,
                    float* __restrict__ A2) {
  const int row = blockIdx.x, t = threadIdx.x;
  const float4* sr = (const float4*)(S + (size_t)row * 2048);
  float4 a = sr[t], b = sr[t + 256];
  float m = fmaxf(fmaxf(fmaxf(a.x, a.y), fmaxf(a.z, a.w)),
                  fmaxf(fmaxf(b.x, b.y), fmaxf(b.z, b.w)));
  m = wave_max(m);
  __shared__ float red[4];
  const int w = t >> 6, lane = t & 63;
  if (!lane) red[w] = m;
  __syncthreads();
  m = fmaxf(fmaxf(red[0], red[1]), fmaxf(red[2], red[3]));
  a.x = __expf(a.x - m); a.y = __expf(a.y - m); a.z = __expf(a.z - m); a.w = __expf(a.w - m);
  b.x = __expf(b.x - m); b.y = __expf(b.y - m); b.z = __expf(b.z - m); b.w = __expf(b.w - m);
  float s = a.x + a.y + a.z + a.w + b.x + b.y + b.z + b.w;
  s = wave_sum(s);
  __syncthreads();
  if (!lane) red[w] = s;
  __syncthreads();
  s = red[0] + red[1] + red[2] + red[3];
  const float inv = 1.f / s;
  a.x *= inv; a.y *= inv; a.z *= inv; a.w *= inv;
  b.x *= inv; b.y *= inv; b.z *= inv; b.w *= inv;
  ushort4 o0, o1;
  o0.x = f2bf(a.x); o0.y = f2bf(a.y); o0.z = f2bf(a.z); o0.w = f2bf(a.w);
  o1.x = f2bf(b.x); o1.y = f2bf(b.y); o1.z = f2bf(b.z); o1.w = f2bf(b.w);
  ((ushort4*)(P + (size_t)row * 2048))[t] = o0;
  ((ushort4*)(P + (size_t)row * 2048))[t + 256] = o1;
  if (A2) {
    float4* ar = (float4*)(A2 + (size_t)row * 2048);
    ar[t] = a;
    ar[t + 256] = b;
  }
}

// ---------------------------------------------------------------------------
__global__ __launch_bounds__(256)
void cast3_kernel(const float* __restrict__ x0, const float* __restrict__ x1,
                  const float* __restrict__ x2, unsigned short* __restrict__ y0,
                  unsigned short* __restrict__ y1, unsigned short* __restrict__ y2) {
  const float* x = blockIdx.y == 0 ? x0 : (blockIdx.y == 1 ? x1 : x2);
  unsigned short* y = blockIdx.y == 0 ? y0 : (blockIdx.y == 1 ? y1 : y2);
  const int i = blockIdx.x * 256 + threadIdx.x;
  const float4 v = ((const float4*)x)[i];
  ushort4 o;
  o.x = f2bf(v.x); o.y = f2bf(v.y); o.z = f2bf(v.z); o.w = f2bf(v.w);
  ((ushort4*)y)[i] = o;
}

struct W8 {
  const float* src[8];
  unsigned short* dst[8];
};

__global__ __launch_bounds__(256)
void transpose_w8_kernel(W8 p) {
  __shared__ unsigned short tile[64][65];
  const float* in = p.src[blockIdx.z];
  unsigned short* out = p.dst[blockIdx.z];
  const int tr0 = blockIdx.y * 64, tc0 = blockIdx.x * 64;
  const int x = threadIdx.x & 63, y = threadIdx.x >> 6;
#pragma unroll
  for (int i = 0; i < 16; ++i) {
    const int r = i * 4 + y;
    tile[r][x] = f2bf(in[(size_t)(tr0 + r) * 1024 + tc0 + x]);
  }
  __syncthreads();
#pragma unroll
  for (int i = 0; i < 16; ++i) {
    const int r = i * 4 + y;
    out[(size_t)(tc0 + r) * 1024 + tr0 + x] = tile[x][r];
  }
}

__global__ __launch_bounds__(256)
void transpose_v8_kernel(const unsigned short* __restrict__ in0,
                         const unsigned short* __restrict__ in1,
                         unsigned short* __restrict__ out0,
                         unsigned short* __restrict__ out1) {
  __shared__ unsigned short tile[64][65];
  const int zz = blockIdx.z & 3;
  const unsigned short* in = (blockIdx.z < 4 ? in0 : in1) + (size_t)zz * 2048 * 1024;
  unsigned short* out = (blockIdx.z < 4 ? out0 : out1) + (size_t)zz * 1024 * 2048;
  const int tr0 = blockIdx.y * 64, tc0 = blockIdx.x * 64;
  const int x = threadIdx.x & 63, y = threadIdx.x >> 6;
#pragma unroll
  for (int i = 0; i < 16; ++i) {
    const int r = i * 4 + y;
    tile[r][x] = in[(size_t)(tr0 + r) * 1024 + tc0 + x];
  }
  __syncthreads();
#pragma unroll
  for (int i = 0; i < 16; ++i) {
    const int r = i * 4 + y;
    out[(size_t)(tc0 + r) * 2048 + tr0 + x] = tile[x][r];
  }
}

// ---------------------------------------------------------------------------
extern "C" void kernel_launch(void* const* d_in, const int* in_sizes, int n_in,
                              void* d_out, int out_size, void* d_ws, size_t ws_size,
                              hipStream_t stream) {
  const float* q = (const float*)d_in[0];
  const float* k = (const float*)d_in[1];
  const float* v = (const float*)d_in[2];
  const float* W[8];
  const float* bW[8];
  for (int i = 0; i < 8; ++i) {
    W[i]  = (const float*)d_in[3 + 2 * i];
    bW[i] = (const float*)d_in[4 + 2 * i];
  }
  const float* g_[6];
  const float* B_[6];
  for (int i = 0; i < 6; ++i) {
    g_[i] = (const float*)d_in[19 + 2 * i];
    B_[i] = (const float*)d_in[20 + 2 * i];
  }

  float* out_p = (float*)d_out;          // (4,2048,1024)
  float* res_p = out_p + 8388608;        // (8192,2048)
  float* a2_p  = res_p + 16777216;       // (4,2048,2048)

  // workspace layout (~338 MB)
  char* ws = (char*)d_ws;
  const size_t MBy = 1u << 20;
  unsigned short* WT   = (unsigned short*)ws;                 // 8 x 2MB
  unsigned short* qb   = (unsigned short*)(ws + 16 * MBy);
  unsigned short* kb   = (unsigned short*)(ws + 32 * MBy);
  unsigned short* vb   = (unsigned short*)(ws + 48 * MBy);
  unsigned short* pb   = (unsigned short*)(ws + 64 * MBy);    // 5 x 16MB proj slices
  float* Sbuf          = (float*)(ws + 64 * MBy);             // 67MB, aliases pb (dead after LN)
  unsigned short* lnq  = (unsigned short*)(ws + 144 * MBy);
  unsigned short* lnk1 = (unsigned short*)(ws + 160 * MBy);
  unsigned short* lnk2 = (unsigned short*)(ws + 176 * MBy);
  unsigned short* lnv1 = (unsigned short*)(ws + 192 * MBy);
  unsigned short* lnv2 = (unsigned short*)(ws + 208 * MBy);
  unsigned short* lnvT1= (unsigned short*)(ws + 224 * MBy);
  unsigned short* lnvT2= (unsigned short*)(ws + 240 * MBy);
  unsigned short* P    = (unsigned short*)(ws + 256 * MBy);   // 33MB
  unsigned short* ofb  = (unsigned short*)(ws + 290 * MBy);
  unsigned short* ob   = (unsigned short*)(ws + 306 * MBy);
  unsigned short* qf2b = (unsigned short*)(ws + 322 * MBy);

  const size_t SL = 8192ull * 1024;  // proj slice elements

  auto gemm = [&](const unsigned short* A, long long sAz,
                  const unsigned short* Bt, long long sBz, const float* bias,
                  float* Cf, long long sCfz, unsigned short* Cb, long long sCbz,
                  float* C2, int offc2, int M, int N, int K, int Z) {
    dim3 grid(N / 128, M / 128, Z);
    g128_bt<<<grid, 256, 0, stream>>>((const short*)A, sAz, (const short*)Bt, sBz,
                                      bias, Cf, sCfz, Cb, sCbz, C2, offc2, N, K);
  };
  LnJob nil{};

  // ---- prep ----
  cast3_kernel<<<dim3(8192, 3), 256, 0, stream>>>(q, k, v, qb, kb, vb);
  W8 w8;
  for (int i = 0; i < 8; ++i) { w8.src[i] = W[i]; w8.dst[i] = WT + (size_t)i * 1048576; }
  transpose_w8_kernel<<<dim3(16, 16, 8), 256, 0, stream>>>(w8);

  // ---- all 5 projections in one dispatch (k1,k2,v1,v2,q1) ----
  {
    Proj5 p;
    p.j[0] = {(const short*)kb, (const short*)(WT + 1u * 1048576), 0, pb + 0 * SL, 0, 0};
    p.j[1] = {(const short*)kb, (const short*)(WT + 5u * 1048576), 0, pb + 1 * SL, 0, 0};
    p.j[2] = {(const short*)vb, (const short*)(WT + 2u * 1048576), 0, pb + 2 * SL, 0, 0};
    p.j[3] = {(const short*)vb, (const short*)(WT + 6u * 1048576), 0, pb + 3 * SL, 0, 0};
    p.j[4] = {(const short*)qb, (const short*)(WT + 0u * 1048576), bW[0], pb + 4 * SL, res_p, 0};
    g128_proj5<<<dim3(8, 64, 5), 256, 0, stream>>>(p);
  }

  // ---- all 5 first-phase LayerNorms in one dispatch ----
  {
    LnJob jk1{pb + 0 * SL, bW[1], g_[1], B_[1], lnk1, 1.f};
    LnJob jk2{pb + 1 * SL, bW[5], g_[4], B_[4], lnk2, 1.f};
    LnJob jv1{pb + 2 * SL, bW[2], g_[2], B_[2], lnv1, 1.f};
    LnJob jv2{pb + 3 * SL, bW[6], g_[5], B_[5], lnv2, 1.f};
    LnJob jq1{pb + 4 * SL, 0,     g_[0], B_[0], lnq,  1.f / 32.f};
    ln_multi<<<dim3(8192, 5), 256, 0, stream>>>(jk1, jk2, jv1, jv2, jq1);
  }
  transpose_v8_kernel<<<dim3(16, 32, 8), 256, 0, stream>>>(lnv1, lnv2, lnvT1, lnvT2);

  // ---- layer 1 attention ----
  gemm(lnq, 2048ll * 1024, lnk1, 2048ll * 1024, 0, Sbuf, 2048ll * 2048, 0, 0, 0, 0,
       2048, 2048, 1024, 4);
  softmax_kernel<<<8192, 256, 0, stream>>>(Sbuf, P, (float*)0);
  gemm(P, 2048ll * 2048, lnvT1, 1024ll * 2048, 0, 0, 0, ob, 2048ll * 1024, 0, 0,
       2048, 1024, 2048, 4);
  gemm(ob, 0, WT + 3u * 1048576, 0, bW[3], 0, 0, ofb, 0, 0, 0, 8192, 1024, 1024, 1);

  // ---- layer 2 ----
  gemm(ofb, 0, WT + 4u * 1048576, 0, bW[4], 0, 0, qf2b, 0, res_p, 1024, 8192, 1024, 1024, 1);
  {
    LnJob jq2{qf2b, 0, g_[3], B_[3], lnq, 1.f / 32.f};
    ln_multi<<<dim3(8192, 1), 256, 0, stream>>>(jq2, nil, nil, nil, nil);
  }
  gemm(lnq, 2048ll * 1024, lnk2, 2048ll * 1024, 0, Sbuf, 2048ll * 2048, 0, 0, 0, 0,
       2048, 2048, 1024, 4);
  softmax_kernel<<<8192, 256, 0, stream>>>(Sbuf, P, a2_p);
  gemm(P, 2048ll * 2048, lnvT2, 1024ll * 2048, 0, 0, 0, ob, 2048ll * 1024, 0, 0,
       2048, 1024, 2048, 4);
  gemm(ob, 0, WT + 7u * 1048576, 0, bW[7], out_p, 0, 0, 0, 0, 0, 8192, 1024, 1024, 1);
}

// Round 3
// 859.119 us; speedup vs baseline: 1.1390x; 1.0043x over previous
//
#include <hip/hip_runtime.h>

#define DEV __device__ __forceinline__

using short8  = __attribute__((ext_vector_type(8))) short;
using floatx4 = __attribute__((ext_vector_type(4))) float;

DEV unsigned short f2bf(float f) {
  unsigned int u = __float_as_uint(f);
  u += 0x7FFFu + ((u >> 16) & 1u);
  return (unsigned short)(u >> 16);
}
DEV float bf2f(unsigned short u) { return __uint_as_float(((unsigned int)u) << 16); }

DEV void stage16(void* lds, const void* g) {
  __builtin_amdgcn_global_load_lds(
      (__attribute__((address_space(1))) void*)g,
      (__attribute__((address_space(3))) void*)lds, 16, 0, 0);
}

DEV float wave_sum(float x) {
#pragma unroll
  for (int m = 32; m; m >>= 1) x += __shfl_xor(x, m);
  return x;
}
DEV float wave_max(float x) {
#pragma unroll
  for (int m = 32; m; m >>= 1) x = fmaxf(x, __shfl_xor(x, m));
  return x;
}

// ---------------------------------------------------------------------------
// Pipelined 128x128 GEMM core: C = A (MxK, K-major) * Bt^T (Bt NxK).
// BK=32, 4 waves, 3 LDS buffers (48 KB -> 3 blocks/CU), 2-tile-deep
// global_load_lds prefetch with counted vmcnt(4) (drains to 0 only at the
// tail), one s_barrier per K-tile.
// CRITICAL ORDER (m201 template): ds_read(kt) BEFORE stage(kt+2) in program
// order, so the compiler cannot insert a conservative vmcnt(0) between the
// in-flight DMA LDS-writes and the fragment reads (the r2 failure mode:
// that drain serialized every K-step on full load latency).
// Race-freedom: lgkmcnt(0) precedes the MFMAs, hence precedes the
// end-of-iteration barrier => all reads of tile kt-1 are complete before
// any wave (post-barrier) stages tile kt+2 into that buffer. Each wave's
// vmcnt(4) before the barrier => its 4 loads of tile kt+1 landed; after the
// barrier ALL waves' tile-kt+1 loads have landed.
// LDS layout: 16x32 bf16 subtiles (1 KB), col ^= 16 when (row&8) ->
// bank-balanced ds_read_b128 AND contiguous-per-lane DMA writes.
// ---------------------------------------------------------------------------
DEV void g128_core(const short* __restrict__ A, const short* __restrict__ Bt,
                   const float* __restrict__ bias,
                   float* __restrict__ Cf, unsigned short* __restrict__ Cb,
                   float* __restrict__ C2, int offc2,
                   int N, int K, int m0, int n0) {
  __shared__ __align__(16) short lds[3][8192];  // per buf: A[0..4095], B[4096..8191]

  const int t    = threadIdx.x;
  const int lane = t & 63;
  const int w    = t >> 6;        // 0..3
  const int wm   = w >> 1;        // 0..1 : owns rows wm*64..+63
  const int wn   = w & 1;         // 0..1 : owns cols wn*64..+63
  const int NT   = K >> 5;        // K-tiles of 32

  // staging geometry: waves 0,1 stage A (8 subtiles), waves 2,3 stage B.
  // wave stages 4 subtiles; lane l writes subtile bytes l*16..+15:
  //   r = l>>2, slot-col = (l&3)*8, holding global col ((l&3)*8)^((l>>5)<<4).
  const int isB  = w >> 1;
  const int row0 = (isB ? n0 : m0) + (w & 1) * 64 + (lane >> 2);
  const int csw  = ((lane & 3) * 8) ^ ((lane >> 5) << 4);
  const short* gbase = isB ? Bt : A;
  const short* gp[4];
#pragma unroll
  for (int i = 0; i < 4; ++i)
    gp[i] = gbase + (size_t)(row0 + i * 16) * K + csw;
  const int ldst = isB * 4096 + (w & 1) * 2048 + lane * 8;

  auto stage = [&](int bi, int tt) {
    short* dst = &lds[bi][ldst];
    const int go = tt * 32;
#pragma unroll
    for (int i = 0; i < 4; ++i)
      stage16(dst + i * 512, gp[i] + go);
  };

  floatx4 acc[4][4];
#pragma unroll
  for (int i = 0; i < 4; ++i)
#pragma unroll
    for (int j = 0; j < 4; ++j)
      acc[i][j] = (floatx4){0.f, 0.f, 0.f, 0.f};

  // prologue: tiles 0,1 in flight; wait tile 0 landed, publish to all waves
  stage(0, 0);
  stage(1, 1);
  asm volatile("s_waitcnt vmcnt(4)" ::: "memory");
  __builtin_amdgcn_s_barrier();

  // fragment read offset within a subtile-row block:
  //   row = base + mr, k-col = q*8 (swizzled)
  const int mr = lane & 15, q = lane >> 4;
  const int fo = mr * 32 + ((q * 8) ^ ((mr & 8) << 1));

  int cur = 0;
  for (int kt = 0; kt < NT; ++kt) {
    // 1) fragment reads of tile kt (program-order FIRST)
    const short* bufA = &lds[cur][wm * 2048];
    const short* bufB = &lds[cur][4096 + wn * 2048];
    short8 a[4], b[4];
#pragma unroll
    for (int m = 0; m < 4; ++m) a[m] = *(const short8*)&bufA[m * 512 + fo];
#pragma unroll
    for (int n = 0; n < 4; ++n) b[n] = *(const short8*)&bufB[n * 512 + fo];

    // 2) issue prefetch of tile kt+2 into the retired buffer
    if (kt + 2 < NT) {
      int b2 = cur + 2; if (b2 >= 3) b2 -= 3;
      stage(b2, kt + 2);
    }

    // 3) my reads are in registers; compute
    asm volatile("s_waitcnt lgkmcnt(0)" ::: "memory");
    __builtin_amdgcn_sched_barrier(0);
    __builtin_amdgcn_s_setprio(1);
#pragma unroll
    for (int m = 0; m < 4; ++m)
#pragma unroll
      for (int n = 0; n < 4; ++n)
        acc[m][n] = __builtin_amdgcn_mfma_f32_16x16x32_bf16(a[m], b[n], acc[m][n], 0, 0, 0);
    __builtin_amdgcn_s_setprio(0);

    // 4) tile kt+1 landed (counted, never 0 in steady state), publish
    if (kt + 1 < NT) {
      if (kt + 2 < NT) asm volatile("s_waitcnt vmcnt(4)" ::: "memory");
      else             asm volatile("s_waitcnt vmcnt(0)" ::: "memory");
      __builtin_amdgcn_s_barrier();
    }
    cur = (cur + 1 == 3) ? 0 : cur + 1;
  }

  // D layout: col=lane&15, row=(lane>>4)*4+reg  [measured m89/m91]
#pragma unroll
  for (int m = 0; m < 4; ++m) {
#pragma unroll
    for (int r = 0; r < 4; ++r) {
      const int row = m0 + wm * 64 + m * 16 + q * 4 + r;
#pragma unroll
      for (int n = 0; n < 4; ++n) {
        const int col = n0 + wn * 64 + n * 16 + mr;
        float vv = acc[m][n][r];
        if (bias) vv += bias[col];
        if (Cf) Cf[(size_t)row * N + col] = vv;
        if (Cb) Cb[(size_t)row * N + col] = f2bf(vv);
        if (C2) C2[(size_t)row * 2048 + offc2 + col] = vv;
      }
    }
  }
}

// bijective XCD-aware swizzle of the flattened block id (m204 form)
DEV void xcd_decode(int gx, int gy, int& bx, int& by, int& bz) {
  const int nwg = gx * gy * gridDim.z;
  int bid = ((int)blockIdx.z * gy + (int)blockIdx.y) * gx + (int)blockIdx.x;
  const int qq = nwg >> 3, rr = nwg & 7;
  const int xcd = bid & 7, jj = bid >> 3;
  bid = (xcd < rr ? xcd * (qq + 1) : rr * (qq + 1) + (xcd - rr) * qq) + jj;
  bx = bid % gx;
  const int tmp = bid / gx;
  by = tmp % gy;
  bz = tmp / gy;
}

__global__ __launch_bounds__(256)
void g128_bt(const short* __restrict__ A, long long sAz,
             const short* __restrict__ Bt, long long sBz,
             const float* __restrict__ bias,
             float* __restrict__ Cf, long long sCfz,
             unsigned short* __restrict__ Cb, long long sCbz,
             float* __restrict__ C2, int offc2,
             int N, int K) {
  int bx, by, bz;
  xcd_decode(gridDim.x, gridDim.y, bx, by, bz);
  g128_core(A + (long long)bz * sAz, Bt + (long long)bz * sBz, bias,
            Cf ? Cf + (long long)bz * sCfz : (float*)0,
            Cb ? Cb + (long long)bz * sCbz : (unsigned short*)0,
            C2, offc2, N, K, by * 128, bx * 128);
}

// 5 independent projection jobs in one dispatch (M=8192, N=1024, K=1024 each)
struct ProjJob {
  const short* A;
  const short* Bt;
  const float* bias;
  unsigned short* Cb;
  float* C2;
  long long offc2;
};
struct Proj5 { ProjJob j[5]; };

__global__ __launch_bounds__(256)
void g128_proj5(Proj5 p) {
  int bx, by, bz;
  xcd_decode(gridDim.x, gridDim.y, bx, by, bz);
  ProjJob jb = p.j[0];
#pragma unroll
  for (int i = 1; i < 5; ++i)
    if (bz == i) jb = p.j[i];
  g128_core(jb.A, jb.Bt, jb.bias, (float*)0, jb.Cb, jb.C2, (int)jb.offc2,
            1024, 1024, by * 128, bx * 128);
}

// ---------------------------------------------------------------------------
// Multi-job LayerNorm over D=1024, bf16 in (opt. +f32 bias before stats) -> bf16
// ---------------------------------------------------------------------------
struct LnJob {
  const unsigned short* x;  // ld = 1024
  const float* bias;        // optional, added before stats
  const float* g;
  const float* Bb;
  unsigned short* y;        // ld = 1024
  float scale;
};

__global__ __launch_bounds__(256)
void ln_multi(LnJob j0, LnJob j1, LnJob j2, LnJob j3, LnJob j4) {
  LnJob jb = j0;
  if (blockIdx.y == 1) jb = j1;
  else if (blockIdx.y == 2) jb = j2;
  else if (blockIdx.y == 3) jb = j3;
  else if (blockIdx.y == 4) jb = j4;
  const int row = blockIdx.x, t = threadIdx.x;
  const ushort4 xv = ((const ushort4*)(jb.x + (size_t)row * 1024))[t];
  float4 v = {bf2f(xv.x), bf2f(xv.y), bf2f(xv.z), bf2f(xv.w)};
  if (jb.bias) {
    const float4 b4 = ((const float4*)jb.bias)[t];
    v.x += b4.x; v.y += b4.y; v.z += b4.z; v.w += b4.w;
  }
  float s  = v.x + v.y + v.z + v.w;
  float s2 = v.x * v.x + v.y * v.y + v.z * v.z + v.w * v.w;
  s = wave_sum(s);
  s2 = wave_sum(s2);
  __shared__ float r1[4], r2[4];
  const int w = t >> 6, lane = t & 63;
  if (!lane) { r1[w] = s; r2[w] = s2; }
  __syncthreads();
  s  = r1[0] + r1[1] + r1[2] + r1[3];
  s2 = r2[0] + r2[1] + r2[2] + r2[3];
  const float mean = s * (1.f / 1024.f);
  const float var  = s2 * (1.f / 1024.f) - mean * mean;
  const float rstd = 1.f / sqrtf(var + 1e-6f);
  const float4 g4 = ((const float4*)jb.g)[t];
  const float4 b4 = ((const float4*)jb.Bb)[t];
  ushort4 o;
  o.x = f2bf(((v.x - mean) * rstd * g4.x + b4.x) * jb.scale);
  o.y = f2bf(((v.y - mean) * rstd * g4.y + b4.y) * jb.scale);
  o.z = f2bf(((v.z - mean) * rstd * g4.z + b4.z) * jb.scale);
  o.w = f2bf(((v.w - mean) * rstd * g4.w + b4.w) * jb.scale);
  ((ushort4*)(jb.y + (size_t)row * 1024))[t] = o;
}

// ---------------------------------------------------------------------------
// Row softmax over 2048 f32 -> bf16 P (+ optional f32 a2 copy)
// ---------------------------------------------------------------------------
__global__ __launch_bounds__(256)
void softmax_kernel(const float* __restrict__ S, unsigned short* __restrict__ P,
                    float* __restrict__ A2) {
  const int row = blockIdx.x, t = threadIdx.x;
  const float4* sr = (const float4*)(S + (size_t)row * 2048);
  float4 a = sr[t], b = sr[t + 256];
  float m = fmaxf(fmaxf(fmaxf(a.x, a.y), fmaxf(a.z, a.w)),
                  fmaxf(fmaxf(b.x, b.y), fmaxf(b.z, b.w)));
  m = wave_max(m);
  __shared__ float red[4];
  const int w = t >> 6, lane = t & 63;
  if (!lane) red[w] = m;
  __syncthreads();
  m = fmaxf(fmaxf(red[0], red[1]), fmaxf(red[2], red[3]));
  a.x = __expf(a.x - m); a.y = __expf(a.y - m); a.z = __expf(a.z - m); a.w = __expf(a.w - m);
  b.x = __expf(b.x - m); b.y = __expf(b.y - m); b.z = __expf(b.z - m); b.w = __expf(b.w - m);
  float s = a.x + a.y + a.z + a.w + b.x + b.y + b.z + b.w;
  s = wave_sum(s);
  __syncthreads();
  if (!lane) red[w] = s;
  __syncthreads();
  s = red[0] + red[1] + red[2] + red[3];
  const float inv = 1.f / s;
  a.x *= inv; a.y *= inv; a.z *= inv; a.w *= inv;
  b.x *= inv; b.y *= inv; b.z *= inv; b.w *= inv;
  ushort4 o0, o1;
  o0.x = f2bf(a.x); o0.y = f2bf(a.y); o0.z = f2bf(a.z); o0.w = f2bf(a.w);
  o1.x = f2bf(b.x); o1.y = f2bf(b.y); o1.z = f2bf(b.z); o1.w = f2bf(b.w);
  ((ushort4*)(P + (size_t)row * 2048))[t] = o0;
  ((ushort4*)(P + (size_t)row * 2048))[t + 256] = o1;
  if (A2) {
    float4* ar = (float4*)(A2 + (size_t)row * 2048);
    ar[t] = a;
    ar[t + 256] = b;
  }
}

// ---------------------------------------------------------------------------
__global__ __launch_bounds__(256)
void cast3_kernel(const float* __restrict__ x0, const float* __restrict__ x1,
                  const float* __restrict__ x2, unsigned short* __restrict__ y0,
                  unsigned short* __restrict__ y1, unsigned short* __restrict__ y2) {
  const float* x = blockIdx.y == 0 ? x0 : (blockIdx.y == 1 ? x1 : x2);
  unsigned short* y = blockIdx.y == 0 ? y0 : (blockIdx.y == 1 ? y1 : y2);
  const int i = blockIdx.x * 256 + threadIdx.x;
  const float4 v = ((const float4*)x)[i];
  ushort4 o;
  o.x = f2bf(v.x); o.y = f2bf(v.y); o.z = f2bf(v.z); o.w = f2bf(v.w);
  ((ushort4*)y)[i] = o;
}

struct W8 {
  const float* src[8];
  unsigned short* dst[8];
};

__global__ __launch_bounds__(256)
void transpose_w8_kernel(W8 p) {
  __shared__ unsigned short tile[64][65];
  const float* in = p.src[blockIdx.z];
  unsigned short* out = p.dst[blockIdx.z];
  const int tr0 = blockIdx.y * 64, tc0 = blockIdx.x * 64;
  const int x = threadIdx.x & 63, y = threadIdx.x >> 6;
#pragma unroll
  for (int i = 0; i < 16; ++i) {
    const int r = i * 4 + y;
    tile[r][x] = f2bf(in[(size_t)(tr0 + r) * 1024 + tc0 + x]);
  }
  __syncthreads();
#pragma unroll
  for (int i = 0; i < 16; ++i) {
    const int r = i * 4 + y;
    out[(size_t)(tc0 + r) * 1024 + tr0 + x] = tile[x][r];
  }
}

__global__ __launch_bounds__(256)
void transpose_v8_kernel(const unsigned short* __restrict__ in0,
                         const unsigned short* __restrict__ in1,
                         unsigned short* __restrict__ out0,
                         unsigned short* __restrict__ out1) {
  __shared__ unsigned short tile[64][65];
  const int zz = blockIdx.z & 3;
  const unsigned short* in = (blockIdx.z < 4 ? in0 : in1) + (size_t)zz * 2048 * 1024;
  unsigned short* out = (blockIdx.z < 4 ? out0 : out1) + (size_t)zz * 1024 * 2048;
  const int tr0 = blockIdx.y * 64, tc0 = blockIdx.x * 64;
  const int x = threadIdx.x & 63, y = threadIdx.x >> 6;
#pragma unroll
  for (int i = 0; i < 16; ++i) {
    const int r = i * 4 + y;
    tile[r][x] = in[(size_t)(tr0 + r) * 1024 + tc0 + x];
  }
  __syncthreads();
#pragma unroll
  for (int i = 0; i < 16; ++i) {
    const int r = i * 4 + y;
    out[(size_t)(tc0 + r) * 2048 + tr0 + x] = tile[x][r];
  }
}

// ---------------------------------------------------------------------------
extern "C" void kernel_launch(void* const* d_in, const int* in_sizes, int n_in,
                              void* d_out, int out_size, void* d_ws, size_t ws_size,
                              hipStream_t stream) {
  const float* q = (const float*)d_in[0];
  const float* k = (const float*)d_in[1];
  const float* v = (const float*)d_in[2];
  const float* W[8];
  const float* bW[8];
  for (int i = 0; i < 8; ++i) {
    W[i]  = (const float*)d_in[3 + 2 * i];
    bW[i] = (const float*)d_in[4 + 2 * i];
  }
  const float* g_[6];
  const float* B_[6];
  for (int i = 0; i < 6; ++i) {
    g_[i] = (const float*)d_in[19 + 2 * i];
    B_[i] = (const float*)d_in[20 + 2 * i];
  }

  float* out_p = (float*)d_out;          // (4,2048,1024)
  float* res_p = out_p + 8388608;        // (8192,2048)
  float* a2_p  = res_p + 16777216;       // (4,2048,2048)

  // workspace layout (~338 MB)
  char* ws = (char*)d_ws;
  const size_t MBy = 1u << 20;
  unsigned short* WT   = (unsigned short*)ws;                 // 8 x 2MB
  unsigned short* qb   = (unsigned short*)(ws + 16 * MBy);
  unsigned short* kb   = (unsigned short*)(ws + 32 * MBy);
  unsigned short* vb   = (unsigned short*)(ws + 48 * MBy);
  unsigned short* pb   = (unsigned short*)(ws + 64 * MBy);    // 5 x 16MB proj slices
  float* Sbuf          = (float*)(ws + 64 * MBy);             // 67MB, aliases pb (dead after LN)
  unsigned short* lnq  = (unsigned short*)(ws + 144 * MBy);
  unsigned short* lnk1 = (unsigned short*)(ws + 160 * MBy);
  unsigned short* lnk2 = (unsigned short*)(ws + 176 * MBy);
  unsigned short* lnv1 = (unsigned short*)(ws + 192 * MBy);
  unsigned short* lnv2 = (unsigned short*)(ws + 208 * MBy);
  unsigned short* lnvT1= (unsigned short*)(ws + 224 * MBy);
  unsigned short* lnvT2= (unsigned short*)(ws + 240 * MBy);
  unsigned short* P    = (unsigned short*)(ws + 256 * MBy);   // 33MB
  unsigned short* ofb  = (unsigned short*)(ws + 290 * MBy);
  unsigned short* ob   = (unsigned short*)(ws + 306 * MBy);
  unsigned short* qf2b = (unsigned short*)(ws + 322 * MBy);

  const size_t SL = 8192ull * 1024;  // proj slice elements

  auto gemm = [&](const unsigned short* A, long long sAz,
                  const unsigned short* Bt, long long sBz, const float* bias,
                  float* Cf, long long sCfz, unsigned short* Cb, long long sCbz,
                  float* C2, int offc2, int M, int N, int K, int Z) {
    dim3 grid(N / 128, M / 128, Z);
    g128_bt<<<grid, 256, 0, stream>>>((const short*)A, sAz, (const short*)Bt, sBz,
                                      bias, Cf, sCfz, Cb, sCbz, C2, offc2, N, K);
  };
  LnJob nil{};

  // ---- prep ----
  cast3_kernel<<<dim3(8192, 3), 256, 0, stream>>>(q, k, v, qb, kb, vb);
  W8 w8;
  for (int i = 0; i < 8; ++i) { w8.src[i] = W[i]; w8.dst[i] = WT + (size_t)i * 1048576; }
  transpose_w8_kernel<<<dim3(16, 16, 8), 256, 0, stream>>>(w8);

  // ---- all 5 projections in one dispatch (k1,k2,v1,v2,q1) ----
  {
    Proj5 p;
    p.j[0] = {(const short*)kb, (const short*)(WT + 1u * 1048576), 0, pb + 0 * SL, 0, 0};
    p.j[1] = {(const short*)kb, (const short*)(WT + 5u * 1048576), 0, pb + 1 * SL, 0, 0};
    p.j[2] = {(const short*)vb, (const short*)(WT + 2u * 1048576), 0, pb + 2 * SL, 0, 0};
    p.j[3] = {(const short*)vb, (const short*)(WT + 6u * 1048576), 0, pb + 3 * SL, 0, 0};
    p.j[4] = {(const short*)qb, (const short*)(WT + 0u * 1048576), bW[0], pb + 4 * SL, res_p, 0};
    g128_proj5<<<dim3(8, 64, 5), 256, 0, stream>>>(p);
  }

  // ---- all 5 first-phase LayerNorms in one dispatch ----
  {
    LnJob jk1{pb + 0 * SL, bW[1], g_[1], B_[1], lnk1, 1.f};
    LnJob jk2{pb + 1 * SL, bW[5], g_[4], B_[4], lnk2, 1.f};
    LnJob jv1{pb + 2 * SL, bW[2], g_[2], B_[2], lnv1, 1.f};
    LnJob jv2{pb + 3 * SL, bW[6], g_[5], B_[5], lnv2, 1.f};
    LnJob jq1{pb + 4 * SL, 0,     g_[0], B_[0], lnq,  1.f / 32.f};
    ln_multi<<<dim3(8192, 5), 256, 0, stream>>>(jk1, jk2, jv1, jv2, jq1);
  }
  transpose_v8_kernel<<<dim3(16, 32, 8), 256, 0, stream>>>(lnv1, lnv2, lnvT1, lnvT2);

  // ---- layer 1 attention ----
  gemm(lnq, 2048ll * 1024, lnk1, 2048ll * 1024, 0, Sbuf, 2048ll * 2048, 0, 0, 0, 0,
       2048, 2048, 1024, 4);
  softmax_kernel<<<8192, 256, 0, stream>>>(Sbuf, P, (float*)0);
  gemm(P, 2048ll * 2048, lnvT1, 1024ll * 2048, 0, 0, 0, ob, 2048ll * 1024, 0, 0,
       2048, 1024, 2048, 4);
  gemm(ob, 0, WT + 3u * 1048576, 0, bW[3], 0, 0, ofb, 0, 0, 0, 8192, 1024, 1024, 1);

  // ---- layer 2 ----
  gemm(ofb, 0, WT + 4u * 1048576, 0, bW[4], 0, 0, qf2b, 0, res_p, 1024, 8192, 1024, 1024, 1);
  {
    LnJob jq2{qf2b, 0, g_[3], B_[3], lnq, 1.f / 32.f};
    ln_multi<<<dim3(8192, 1), 256, 0, stream>>>(jq2, nil, nil, nil, nil);
  }
  gemm(lnq, 2048ll * 1024, lnk2, 2048ll * 1024, 0, Sbuf, 2048ll * 2048, 0, 0, 0, 0,
       2048, 2048, 1024, 4);
  softmax_kernel<<<8192, 256, 0, stream>>>(Sbuf, P, a2_p);
  gemm(P, 2048ll * 2048, lnvT2, 1024ll * 2048, 0, 0, 0, ob, 2048ll * 1024, 0, 0,
       2048, 1024, 2048, 4);
  gemm(ob, 0, WT + 7u * 1048576, 0, bW[7], out_p, 0, 0, 0, 0, 0, 8192, 1024, 1024, 1);
}